// Round 6
// baseline (84.253 us; speedup 1.0000x reference)
//
#include <hip/hip_runtime.h>

namespace {
constexpr int kB = 8;
constexpr int kC = 1025;
constexpr int kT = 3000;
constexpr int kThreads = 256;              // 4 waves; 8 blocks/CU -> 32 waves/CU
constexpr int kWaves = kThreads / 64;
constexpr int kSeg = kThreads * 4;         // 1024 elements per segment
constexpr int kNSeg = 3;                   // 1024 + 1024 + 952 = 3000
constexpr float kPi = 3.14159265358979323846f;   // 0x40490FDB == np.float32(np.pi)
constexpr float kTwoPi = 6.28318530717958647692f;
constexpr float kPiO2 = 1.57079632679489661923f;
}  // namespace

typedef float v4f __attribute__((ext_vector_type(4)));

// ~2-ulp atan2 on [0,1]-reduced argument (sleef atanf poly), rcp+1 Newton step.
__device__ __forceinline__ float fast_atan2f(float y, float x) {
  const float ax = __builtin_fabsf(x), ay = __builtin_fabsf(y);
  const float mx = fmaxf(ax, ay), mn = fminf(ax, ay);
  float r = __builtin_amdgcn_rcpf(mx);
  r = r * (2.0f - mx * r);                 // Newton: ~0.5 ulp reciprocal
  float t = mn * r;                        // in [0,1]
  if (mx == 0.0f) t = 0.0f;                // atan2(0,0) -> 0
  const float s = t * t;
  float p = 0.00282363896258175373f;
  p = fmaf(p, s, -0.0159569028764963150f);
  p = fmaf(p, s, 0.0425049886107444763f);
  p = fmaf(p, s, -0.0748900920152664185f);
  p = fmaf(p, s, 0.106347933411598206f);
  p = fmaf(p, s, -0.142027363181114197f);
  p = fmaf(p, s, 0.199926957488059998f);
  p = fmaf(p, s, -0.333331018686294556f);
  float a = fmaf(p * s, t, t);             // atan(t)
  a = (ay > ax) ? (kPiO2 - a) : a;
  a = (x < 0.0f) ? (kPi - a) : a;
  return copysignf(a, y);
}

__global__ __launch_bounds__(kThreads, 8) void coherent_polar_kernel(
    const float* __restrict__ xr, const float* __restrict__ xi,
    float* __restrict__ out) {
  __shared__ float s_wsum[kWaves][kNSeg];
  __shared__ float s_wmin[kWaves][kNSeg];
  __shared__ float s_wmax[kWaves][kNSeg];

  const int row = blockIdx.x;              // [0, B*C)
  const int b = row / kC;
  const int c = row - b * kC;
  const float* re = xr + (size_t)row * kT;
  const float* im = xi + (size_t)row * kT;
  float* mag_out = out + ((size_t)b * (2 * kC) + c) * kT;
  float* ph_out  = out + ((size_t)b * (2 * kC) + kC + c) * kT;

  const int tid = threadIdx.x;
  const int lane = tid & 63;
  const int wave = tid >> 6;

  // Thread t owns float4 chunks at s*1024 + 4t for s = 0,1,2.
  // Every global access instruction is wave-contiguous (1 KB per wave).
  bool act[kNSeg];
  int offs[kNSeg];
  float ph[kNSeg][4];
#pragma unroll
  for (int s = 0; s < kNSeg; ++s) {
    offs[s] = s * kSeg + tid * 4;
    act[s] = offs[s] < kT;                 // seg2: tid < 238
    if (act[s]) {
      const v4f r4 = *reinterpret_cast<const v4f*>(re + offs[s]);
      const v4f i4 = *reinterpret_cast<const v4f*>(im + offs[s]);
      v4f m4;
      m4.x = sqrtf(fmaf(r4.x, r4.x, i4.x * i4.x));
      m4.y = sqrtf(fmaf(r4.y, r4.y, i4.y * i4.y));
      m4.z = sqrtf(fmaf(r4.z, r4.z, i4.z * i4.z));
      m4.w = sqrtf(fmaf(r4.w, r4.w, i4.w * i4.w));
      *reinterpret_cast<v4f*>(mag_out + offs[s]) = m4;
      ph[s][0] = fast_atan2f(i4.x, r4.x);
      ph[s][1] = fast_atan2f(i4.y, r4.y);
      ph[s][2] = fast_atan2f(i4.z, r4.z);
      ph[s][3] = fast_atan2f(i4.w, r4.w);
    }
  }

  // ---- Boundary phase (raw) of previous chunk: shfl within wave; lane 0
  // recomputes from a scalar reload (L1-hit: the line was just fetched).
  float prevph[kNSeg];
#pragma unroll
  for (int s = 0; s < kNSeg; ++s) {
    prevph[s] = __shfl_up(ph[s][3], 1);
    if (lane == 0) {
      prevph[s] = (offs[s] == 0) ? ph[s][0]
                                 : fast_atan2f(im[offs[s] - 1], re[offs[s] - 1]);
    }
  }

  // ---- Local unwrap of each 4-chunk (boundary step vs prev chunk included).
  float T[kNSeg];
#pragma unroll
  for (int s = 0; s < kNSeg; ++s) {
    float run = 0.0f;
    if (act[s]) {
      float p = prevph[s];
#pragma unroll
      for (int k = 0; k < 4; ++k) {
        const float cur = ph[s][k];
        const float d = cur - p;
        p = cur;
        float step = 0.0f;
        if (d < -kPi) step = kTwoPi;
        else if (d > kPi) step = -kTwoPi;
        run += step;
        ph[s][k] = cur + run;              // raw + local inclusive correction
      }
    }
    T[s] = act[s] ? run : 0.0f;
  }

  // ---- Wave-level inclusive scan of per-thread step totals (3 at once).
  float inc[kNSeg] = {T[0], T[1], T[2]};
#pragma unroll
  for (int d = 1; d < 64; d <<= 1) {
#pragma unroll
    for (int s = 0; s < kNSeg; ++s) {
      const float n = __shfl_up(inc[s], d);
      if (lane >= d) inc[s] += n;
    }
  }
  float excl[kNSeg];
#pragma unroll
  for (int s = 0; s < kNSeg; ++s) excl[s] = inc[s] - T[s];

  // ---- Wave-relative min/max per segment.
  float mn[kNSeg], mx[kNSeg];
#pragma unroll
  for (int s = 0; s < kNSeg; ++s) {
    mn[s] = __builtin_inff();
    mx[s] = -__builtin_inff();
    if (act[s]) {
#pragma unroll
      for (int k = 0; k < 4; ++k) {
        const float u = ph[s][k] + excl[s];
        mn[s] = fminf(mn[s], u);
        mx[s] = fmaxf(mx[s], u);
      }
    }
  }
#pragma unroll
  for (int m = 32; m >= 1; m >>= 1) {
#pragma unroll
    for (int s = 0; s < kNSeg; ++s) {
      mn[s] = fminf(mn[s], __shfl_xor(mn[s], m));
      mx[s] = fmaxf(mx[s], __shfl_xor(mx[s], m));
    }
  }
  if (lane == 63) {
#pragma unroll
    for (int s = 0; s < kNSeg; ++s) s_wsum[wave][s] = inc[s];
  }
  if (lane == 0) {
#pragma unroll
    for (int s = 0; s < kNSeg; ++s) { s_wmin[wave][s] = mn[s]; s_wmax[wave][s] = mx[s]; }
  }
  __syncthreads();   // the ONLY barrier

  // ---- Combine: wave prefixes + segment bases, global min/max, normalize.
  float ws[kWaves][kNSeg];
#pragma unroll
  for (int w = 0; w < kWaves; ++w)
#pragma unroll
    for (int s = 0; s < kNSeg; ++s) ws[w][s] = s_wsum[w][s];

  float wavePref[kWaves][kNSeg];
  float blockTot[kNSeg];
#pragma unroll
  for (int s = 0; s < kNSeg; ++s) {
    float acc = 0.0f;
#pragma unroll
    for (int w = 0; w < kWaves; ++w) { wavePref[w][s] = acc; acc += ws[w][s]; }
    blockTot[s] = acc;
  }
  float segBase[kNSeg];
  segBase[0] = 0.0f;
  segBase[1] = blockTot[0];
  segBase[2] = blockTot[0] + blockTot[1];

  float gmn = __builtin_inff();
  float gmx = -__builtin_inff();
#pragma unroll
  for (int w = 0; w < kWaves; ++w) {
#pragma unroll
    for (int s = 0; s < kNSeg; ++s) {
      const float off = segBase[s] + wavePref[w][s];
      gmn = fminf(gmn, s_wmin[w][s] + off);
      gmx = fmaxf(gmx, s_wmax[w][s] + off);
    }
  }
  const float inv = 1.0f / (gmx - gmn + 1e-8f);

#pragma unroll
  for (int s = 0; s < kNSeg; ++s) {
    if (act[s]) {
      const float base = segBase[s] + wavePref[wave][s] + excl[s] - gmn;
      v4f o;
      o.x = (ph[s][0] + base) * inv;
      o.y = (ph[s][1] + base) * inv;
      o.z = (ph[s][2] + base) * inv;
      o.w = (ph[s][3] + base) * inv;
      *reinterpret_cast<v4f*>(ph_out + offs[s]) = o;
    }
  }
}

extern "C" void kernel_launch(void* const* d_in, const int* in_sizes, int n_in,
                              void* d_out, int out_size, void* d_ws, size_t ws_size,
                              hipStream_t stream) {
  const float* xr = (const float*)d_in[0];
  const float* xi = (const float*)d_in[1];
  float* out = (float*)d_out;
  coherent_polar_kernel<<<dim3(kB * kC), dim3(kThreads), 0, stream>>>(xr, xi, out);
}

// Round 7
// 80.210 us; speedup vs baseline: 1.0504x; 1.0504x over previous
//
#include <hip/hip_runtime.h>

namespace {
constexpr int kB = 8;
constexpr int kC = 1025;
constexpr int kT = 3000;
constexpr int kThreads = 256;              // 4 waves
constexpr int kWaves = kThreads / 64;
constexpr int kSeg = kThreads * 4;         // 1024 elements per segment
constexpr int kNSeg = 3;                   // 1024 + 1024 + 952 = 3000
constexpr float kPi = 3.14159265358979323846f;   // 0x40490FDB == np.float32(np.pi)
constexpr float kTwoPi = 6.28318530717958647692f;
constexpr float kPiO2 = 1.57079632679489661923f;
}  // namespace

typedef float v4f __attribute__((ext_vector_type(4)));
typedef float v2f __attribute__((ext_vector_type(2)));

// atan core on t in [0,1], 2 lanes packed -> v_pk_fma_f32 candidates.
// (-ffp-contract is on by default: p*s + c fuses.)
__device__ __forceinline__ v2f atan_core2(v2f t) {
  const v2f s = t * t;
  v2f p = v2f{0.00282363896258175373f, 0.00282363896258175373f};
  p = p * s + v2f{-0.0159569028764963150f, -0.0159569028764963150f};
  p = p * s + v2f{0.0425049886107444763f, 0.0425049886107444763f};
  p = p * s + v2f{-0.0748900920152664185f, -0.0748900920152664185f};
  p = p * s + v2f{0.106347933411598206f, 0.106347933411598206f};
  p = p * s + v2f{-0.142027363181114197f, -0.142027363181114197f};
  p = p * s + v2f{0.199926957488059998f, 0.199926957488059998f};
  p = p * s + v2f{-0.333331018686294556f, -0.333331018686294556f};
  return (p * s) * t + t;                  // atan(t)
}

// 4-wide atan2: scalar octant reduction (rcp, no Newton: v_rcp_f32 ~1 ulp),
// packed polynomial, scalar epilogue.
__device__ __forceinline__ void fast_atan2_4(const v4f y4, const v4f x4,
                                             float out[4]) {
  float t[4], ax[4], ay[4];
  const float xs[4] = {x4.x, x4.y, x4.z, x4.w};
  const float ys[4] = {y4.x, y4.y, y4.z, y4.w};
#pragma unroll
  for (int k = 0; k < 4; ++k) {
    ax[k] = __builtin_fabsf(xs[k]);
    ay[k] = __builtin_fabsf(ys[k]);
    const float mx = fmaxf(ax[k], ay[k]);
    const float mn = fminf(ax[k], ay[k]);
    float tt = mn * __builtin_amdgcn_rcpf(mx);
    if (mx == 0.0f) tt = 0.0f;             // atan2(0,0) -> 0 (avoid 0*inf NaN)
    t[k] = tt;
  }
  const v2f a01 = atan_core2(v2f{t[0], t[1]});
  const v2f a23 = atan_core2(v2f{t[2], t[3]});
  const float av[4] = {a01.x, a01.y, a23.x, a23.y};
#pragma unroll
  for (int k = 0; k < 4; ++k) {
    float a = av[k];
    a = (ay[k] > ax[k]) ? (kPiO2 - a) : a;
    a = (xs[k] < 0.0f) ? (kPi - a) : a;
    out[k] = copysignf(a, ys[k]);
  }
}

__global__ __launch_bounds__(kThreads, 8) void coherent_polar_kernel(
    const float* __restrict__ xr, const float* __restrict__ xi,
    float* __restrict__ out) {
  __shared__ float s_last[kNSeg][kThreads];   // raw tail phase per (seg, thread)
  __shared__ float s_wsum[kWaves][kNSeg];
  __shared__ float s_wmin[kWaves][kNSeg];
  __shared__ float s_wmax[kWaves][kNSeg];

  const int row = blockIdx.x;              // [0, B*C)
  const int b = row / kC;
  const int c = row - b * kC;
  const float* re = xr + (size_t)row * kT;
  const float* im = xi + (size_t)row * kT;
  float* mag_out = out + ((size_t)b * (2 * kC) + c) * kT;
  float* ph_out  = out + ((size_t)b * (2 * kC) + kC + c) * kT;

  const int tid = threadIdx.x;
  const int lane = tid & 63;
  const int wave = tid >> 6;

  bool act[kNSeg];
  int offs[kNSeg];
#pragma unroll
  for (int s = 0; s < kNSeg; ++s) {
    offs[s] = s * kSeg + tid * 4;
    act[s] = offs[s] < kT;                 // seg2: tid < 238
  }

  // ---- Prefetch all global loads (wave-contiguous 1KB per instruction).
  v4f r4[kNSeg], i4[kNSeg];
#pragma unroll
  for (int s = 0; s < kNSeg; ++s) {
    if (act[s]) {
      r4[s] = *reinterpret_cast<const v4f*>(re + offs[s]);
      i4[s] = *reinterpret_cast<const v4f*>(im + offs[s]);
    }
  }

  // ---- Magnitude out + raw phases to registers.
  float ph[kNSeg][4];
#pragma unroll
  for (int s = 0; s < kNSeg; ++s) {
    if (act[s]) {
      v4f m4;
      m4.x = __builtin_amdgcn_sqrtf(fmaf(r4[s].x, r4[s].x, i4[s].x * i4[s].x));
      m4.y = __builtin_amdgcn_sqrtf(fmaf(r4[s].y, r4[s].y, i4[s].y * i4[s].y));
      m4.z = __builtin_amdgcn_sqrtf(fmaf(r4[s].z, r4[s].z, i4[s].z * i4[s].z));
      m4.w = __builtin_amdgcn_sqrtf(fmaf(r4[s].w, r4[s].w, i4[s].w * i4[s].w));
      *reinterpret_cast<v4f*>(mag_out + offs[s]) = m4;
      fast_atan2_4(i4[s], r4[s], ph[s]);
    }
  }

  // ---- Boundary handoff via LDS: prev raw phase for chunk (s, tid).
#pragma unroll
  for (int s = 0; s < kNSeg; ++s) s_last[s][tid] = act[s] ? ph[s][3] : 0.0f;
  __syncthreads();
  float prevph[kNSeg];
#pragma unroll
  for (int s = 0; s < kNSeg; ++s) {
    if (tid > 0)       prevph[s] = s_last[s][tid - 1];
    else if (s > 0)    prevph[s] = s_last[s - 1][kThreads - 1];
    else               prevph[s] = ph[0][0];   // element 0: step = 0
  }

  // ---- Local unwrap of each 4-chunk (boundary step included).
  float T[kNSeg];
#pragma unroll
  for (int s = 0; s < kNSeg; ++s) {
    float run = 0.0f;
    if (act[s]) {
      float p = prevph[s];
#pragma unroll
      for (int k = 0; k < 4; ++k) {
        const float cur = ph[s][k];
        const float d = cur - p;
        p = cur;
        float step = 0.0f;
        if (d < -kPi) step = kTwoPi;
        else if (d > kPi) step = -kTwoPi;
        run += step;
        ph[s][k] = cur + run;              // raw + local inclusive correction
      }
    }
    T[s] = act[s] ? run : 0.0f;
  }

  // ---- Wave-level inclusive scan of per-thread step totals (3 at once).
  float inc[kNSeg] = {T[0], T[1], T[2]};
#pragma unroll
  for (int d = 1; d < 64; d <<= 1) {
#pragma unroll
    for (int s = 0; s < kNSeg; ++s) {
      const float n = __shfl_up(inc[s], d);
      if (lane >= d) inc[s] += n;
    }
  }
  float excl[kNSeg];
#pragma unroll
  for (int s = 0; s < kNSeg; ++s) excl[s] = inc[s] - T[s];

  // ---- Wave-relative min/max per segment.
  float mn[kNSeg], mx[kNSeg];
#pragma unroll
  for (int s = 0; s < kNSeg; ++s) {
    mn[s] = __builtin_inff();
    mx[s] = -__builtin_inff();
    if (act[s]) {
#pragma unroll
      for (int k = 0; k < 4; ++k) {
        const float u = ph[s][k] + excl[s];
        mn[s] = fminf(mn[s], u);
        mx[s] = fmaxf(mx[s], u);
      }
    }
  }
#pragma unroll
  for (int m = 32; m >= 1; m >>= 1) {
#pragma unroll
    for (int s = 0; s < kNSeg; ++s) {
      mn[s] = fminf(mn[s], __shfl_xor(mn[s], m));
      mx[s] = fmaxf(mx[s], __shfl_xor(mx[s], m));
    }
  }
  if (lane == 63) {
#pragma unroll
    for (int s = 0; s < kNSeg; ++s) s_wsum[wave][s] = inc[s];
  }
  if (lane == 0) {
#pragma unroll
    for (int s = 0; s < kNSeg; ++s) { s_wmin[wave][s] = mn[s]; s_wmax[wave][s] = mx[s]; }
  }
  __syncthreads();

  // ---- Combine: wave prefixes + segment bases, global min/max, normalize.
  float wavePref[kWaves][kNSeg];
  float blockTot[kNSeg];
#pragma unroll
  for (int s = 0; s < kNSeg; ++s) {
    float acc = 0.0f;
#pragma unroll
    for (int w = 0; w < kWaves; ++w) { wavePref[w][s] = acc; acc += s_wsum[w][s]; }
    blockTot[s] = acc;
  }
  float segBase[kNSeg];
  segBase[0] = 0.0f;
  segBase[1] = blockTot[0];
  segBase[2] = blockTot[0] + blockTot[1];

  float gmn = __builtin_inff();
  float gmx = -__builtin_inff();
#pragma unroll
  for (int w = 0; w < kWaves; ++w) {
#pragma unroll
    for (int s = 0; s < kNSeg; ++s) {
      const float off = segBase[s] + wavePref[w][s];
      gmn = fminf(gmn, s_wmin[w][s] + off);
      gmx = fmaxf(gmx, s_wmax[w][s] + off);
    }
  }
  const float inv = 1.0f / (gmx - gmn + 1e-8f);

#pragma unroll
  for (int s = 0; s < kNSeg; ++s) {
    if (act[s]) {
      const float base = segBase[s] + wavePref[wave][s] + excl[s] - gmn;
      v4f o;
      o.x = (ph[s][0] + base) * inv;
      o.y = (ph[s][1] + base) * inv;
      o.z = (ph[s][2] + base) * inv;
      o.w = (ph[s][3] + base) * inv;
      *reinterpret_cast<v4f*>(ph_out + offs[s]) = o;
    }
  }
}

extern "C" void kernel_launch(void* const* d_in, const int* in_sizes, int n_in,
                              void* d_out, int out_size, void* d_ws, size_t ws_size,
                              hipStream_t stream) {
  const float* xr = (const float*)d_in[0];
  const float* xi = (const float*)d_in[1];
  float* out = (float*)d_out;
  coherent_polar_kernel<<<dim3(kB * kC), dim3(kThreads), 0, stream>>>(xr, xi, out);
}